// Round 5
// baseline (2121.396 us; speedup 1.0000x reference)
//
#include <hip/hip_runtime.h>

#define AS1 __attribute__((address_space(1)))
#define AS3 __attribute__((address_space(3)))

typedef __attribute__((ext_vector_type(4))) float f32x4;
typedef __attribute__((ext_vector_type(8))) short s16x8;
typedef __attribute__((ext_vector_type(4))) short s16x4;

static constexpr int BB = 256, SS = 128, OBSN = 256, HH = 1024, AN = 18;
static constexpr int MM = BB * SS;   // 32768
static constexpr int G4 = 4 * HH;    // 4096

static constexpr int LP_OFF  = MM * AN;            // 589824
static constexpr int ENT_OFF = LP_OFF + MM;        // 622592
static constexpr int VAL_OFF = ENT_OFF + MM;       // 655360

__device__ __forceinline__ short f2bf(float f) {
  unsigned u = __builtin_bit_cast(unsigned, f);
  u += 0x7FFFu + ((u >> 16) & 1u);
  return (short)(u >> 16);
}
__device__ __forceinline__ float bf2f(short s) {
  unsigned u = ((unsigned)(unsigned short)s) << 16;
  return __builtin_bit_cast(float, u);
}
__device__ __forceinline__ void gl_lds16(const void* g, void* l) {
  __builtin_amdgcn_global_load_lds((const AS1 void*)g, (AS3 void*)l, 16, 0, 0);
}
__device__ __forceinline__ float sigf(float x) {
  x = fminf(fmaxf(x, -30.f), 30.f);
  return 1.f / (1.f + __expf(-x));
}
__device__ __forceinline__ float tanhfast(float x) {
  x = fminf(fmaxf(x, -15.f), 15.f);
  float e = __expf(2.f * x);
  return (e - 1.f) / (e + 1.f);
}
__device__ __forceinline__ void cast4(const float* __restrict__ s,
                                      short* __restrict__ d, int i) {
  f32x4 v = ((const f32x4*)s)[i];
  s16x4 o;
  o[0] = f2bf(v[0]); o[1] = f2bf(v[1]); o[2] = f2bf(v[2]); o[3] = f2bf(v[3]);
  ((s16x4*)d)[i] = o;
}

// ---------------- prep: casts + bias fold + state init --------------------
__global__ __launch_bounds__(256) void prep(
    const float* __restrict__ obs, const float* __restrict__ Wb,
    const float* __restrict__ Wih, const float* __restrict__ Whh,
    const float* __restrict__ Wl, const float* __restrict__ Wv,
    const float* __restrict__ bih, const float* __restrict__ bhh,
    const float* __restrict__ hx, const float* __restrict__ cx,
    short* __restrict__ obsb, short* __restrict__ wbo, short* __restrict__ wiho,
    short* __restrict__ whho, short* __restrict__ wlo, short* __restrict__ wvo,
    float* __restrict__ bsum, short* __restrict__ h0o, float* __restrict__ co) {
  int i = blockIdx.x * 256 + threadIdx.x;   // float4 units
  if (i < 2097152) { cast4(obs, obsb, i); return; }
  i -= 2097152;
  if (i < 65536) { cast4(Wb, wbo, i); return; }
  i -= 65536;
  if (i < 1048576) { cast4(Wih, wiho, i); return; }
  i -= 1048576;
  if (i < 1048576) { cast4(Whh, whho, i); return; }
  i -= 1048576;
  if (i < 4608) { cast4(Wl, wlo, i); return; }
  i -= 4608;
  if (i < 256) { cast4(Wv, wvo, i); return; }
  i -= 256;
  if (i < 1024) {
    f32x4 a = ((const f32x4*)bih)[i];
    f32x4 b = ((const f32x4*)bhh)[i];
    ((f32x4*)bsum)[i] = a + b;
    return;
  }
  i -= 1024;
  // i < 65536: hx -> h0 bf16, cx -> c f32
  cast4(hx, h0o, i);
  ((f32x4*)co)[i] = ((const f32x4*)cx)[i];
}

// ---------------- bf16 B^T GEMM, 128x128 tile, BK=32 (m97 structure) ------
template <int N, int K, bool RELU, int REMAP>
__global__ __launch_bounds__(256, 2) void gemm_bt(
    const short* __restrict__ A, const short* __restrict__ Bw,
    const float* __restrict__ bias, short* __restrict__ C, int t0) {
  __shared__ short lA[128 * 32];
  __shared__ short lB[128 * 32];
  const int tid = threadIdx.x;
  const int lane = tid & 63, wave = tid >> 6;
  const int nTN = N / 128;
  const int tm = blockIdx.x / nTN, tn = blockIdx.x % nTN;

  const int r0 = tid >> 2;          // 0..63 staging row
  const int kc = (tid & 3) * 8;     // element offset in row

  const int m0 = tm * 128 + r0;
  const int m1 = m0 + 64;
  size_t pr0, pr1;
  if constexpr (REMAP == 1) {
    pr0 = (size_t)((m0 & (BB - 1)) * SS + t0 + (m0 >> 8));
    pr1 = (size_t)((m1 & (BB - 1)) * SS + t0 + (m1 >> 8));
  } else {
    pr0 = (size_t)m0; pr1 = (size_t)m1;
  }
  const short* a0 = A + pr0 * K + kc;
  const short* a1 = A + pr1 * K + kc;
  const short* b0 = Bw + (size_t)(tn * 128 + r0) * K + kc;
  const short* b1 = Bw + (size_t)(tn * 128 + r0 + 64) * K + kc;

  f32x4 acc[4][4];
#pragma unroll
  for (int i = 0; i < 4; ++i)
#pragma unroll
    for (int j = 0; j < 4; ++j) acc[i][j] = {0.f, 0.f, 0.f, 0.f};

  const int wr = (wave >> 1) * 64;
  const int wc = (wave & 1) * 64;
  const int fr = lane & 15;
  const int fk = (lane >> 4) * 8;

  for (int k0 = 0; k0 < K; k0 += 32) {
    __syncthreads();
    gl_lds16(a0 + k0, &lA[tid * 8]);
    gl_lds16(a1 + k0, &lA[2048 + tid * 8]);
    gl_lds16(b0 + k0, &lB[tid * 8]);
    gl_lds16(b1 + k0, &lB[2048 + tid * 8]);
    __syncthreads();
    s16x8 af[4], bfr[4];
#pragma unroll
    for (int i = 0; i < 4; ++i)
      af[i] = *(const s16x8*)&lA[(wr + i * 16 + fr) * 32 + fk];
#pragma unroll
    for (int j = 0; j < 4; ++j)
      bfr[j] = *(const s16x8*)&lB[(wc + j * 16 + fr) * 32 + fk];
#pragma unroll
    for (int i = 0; i < 4; ++i)
#pragma unroll
      for (int j = 0; j < 4; ++j)
        acc[i][j] = __builtin_amdgcn_mfma_f32_16x16x32_bf16(af[i], bfr[j], acc[i][j], 0, 0, 0);
  }

  const int orow = (lane >> 4) * 4;
#pragma unroll
  for (int i = 0; i < 4; ++i) {
#pragma unroll
    for (int j = 0; j < 4; ++j) {
      const int colg = tn * 128 + wc + j * 16 + fr;
      const float bv = bias[colg];
#pragma unroll
      for (int r = 0; r < 4; ++r) {
        const int rowg = tm * 128 + wr + i * 16 + orow + r;
        float v = acc[i][j][r] + bv;
        if (RELU) v = v > 0.f ? v : 0.f;
        C[(size_t)rowg * N + colg] = f2bf(v);
      }
    }
  }
}

// ---------------- persistent LSTM scan v3 ---------------------------------
// 256 WGs x 256 thr. XCD-pinned: xcd=blockIdx&7, bt=xcd>>1 (64 batch rows),
// ht=(xcd&1)*32+(blockIdx>>3) (16 hcols) -> each bt-group on exactly 2 XCDs.
// W slice (4 gates x 16 hcols x 1024 k = 128KB) LDS-resident across steps.
// h staged per 64-k chunk into PER-WAVE ring buffers; counted vmcnt waits.
// Inter-step sync: 64 single-writer flags / bt-group; RELAXED poll + ONE
// release fence (writer) / ONE acquire fence (reader) per step.

#define STAGE_H(kc_, dbuf_)                                                   \
  {                                                                           \
    const int _r = lane >> 3, _cp = lane & 7;                                 \
    const short* _s = hsrc + (size_t)(b0 + w * 16 + _r) * HH + (kc_) * 64 +   \
                      ((_cp ^ _r) << 3);                                      \
    gl_lds16(_s, ring + (dbuf_) * 8192 + w * 2048 + lane * 16);               \
    gl_lds16(_s + (size_t)8 * HH,                                             \
             ring + (dbuf_) * 8192 + w * 2048 + 1024 + lane * 16);            \
  }

#define COMPUTE_CH(kc_, dbuf_)                                                \
  {                                                                           \
    const char* _cur = ring + (dbuf_) * 8192 + w * 2048;                      \
    _Pragma("unroll") for (int kk = 0; kk < 2; ++kk) {                        \
      const int _c = kk * 4 + fh;                                             \
      const s16x8 _af =                                                       \
          *(const s16x8*)(_cur + fr * 128 + ((_c ^ (fr & 7)) << 4));          \
      _Pragma("unroll") for (int j = 0; j < 4; ++j) {                         \
        const int _wr = j * 16 + fr;                                          \
        const s16x8 _bw = *(const s16x8*)(smem + _wr * 2048 +                 \
                               ((((kc_) * 8 + _c) ^ (_wr & 7)) << 4));        \
        acc[j] =                                                              \
            __builtin_amdgcn_mfma_f32_16x16x32_bf16(_af, _bw, acc[j], 0, 0, 0); \
      }                                                                       \
    }                                                                         \
  }

#define WAIT4 asm volatile("s_waitcnt vmcnt(4)" ::: "memory")
#define WAIT2 asm volatile("s_waitcnt vmcnt(2)" ::: "memory")
#define WAIT0 asm volatile("s_waitcnt vmcnt(0)" ::: "memory")

__global__ __launch_bounds__(256, 1) void lstm_scan(
    const short* __restrict__ Whh, const short* __restrict__ xg,
    short* __restrict__ hs, const short* __restrict__ h0,
    float* __restrict__ cst, int* __restrict__ bar, int nsteps, int t0) {
  extern __shared__ char smem[];
  char* ring = smem + 131072;               // 3 x 8192 B h ring (per-wave 2KB)

  const int tid = threadIdx.x, lane = tid & 63, w = tid >> 6;
  const int xcd = blockIdx.x & 7;
  const int bt = xcd >> 1;
  const int ht = (xcd & 1) * 32 + (blockIdx.x >> 3);
  const int b0 = bt * 64, hc0 = ht * 16;
  const int fr = lane & 15, fh = lane >> 4;

  // --- W preload: LDS row r = gate(r>>4), hcol hc0+(r&15); 32 rounds ---
#pragma unroll 4
  for (int j = 0; j < 32; ++j) {
    const int cid = j * 256 + tid;
    const int r = cid >> 7, cc = cid & 127;
    const int wrow = (r >> 4) * HH + hc0 + (r & 15);
    gl_lds16(Whh + (size_t)wrow * HH + ((cc ^ (r & 7)) << 3), smem + cid * 16);
  }
  const int brow = b0 + w * 16 + fh * 4;    // + r
  const int hcol = hc0 + fr;
  float cv[4];
#pragma unroll
  for (int r = 0; r < 4; ++r) cv[r] = cst[(size_t)(brow + r) * HH + hcol];
  int* flags = bar + bt * 64;
  __syncthreads();                           // W + cv ready

  for (int sl = 0; sl < nsteps; ++sl) {
    const short* hsrc = (sl == 0) ? h0 : hs + (size_t)(sl - 1) * (BB * HH);
    f32x4 acc[4];
#pragma unroll
    for (int j = 0; j < 4; ++j) acc[j] = {0.f, 0.f, 0.f, 0.f};

    STAGE_H(0, 0);
    STAGE_H(1, 1);
    STAGE_H(2, 2);
    // xg preload (overlaps staging; forces over-wait only at first vmcnt)
    float xgv[4][4];
    {
      const short* xgb = xg + (size_t)sl * BB * G4;
#pragma unroll
      for (int j = 0; j < 4; ++j)
#pragma unroll
        for (int r = 0; r < 4; ++r)
          xgv[j][r] = bf2f(xgb[(size_t)(brow + r) * G4 + j * HH + hcol]);
    }

    for (int t = 0; t < 4; ++t) {            // chunks 0..11, depth-3 ring
      const int kc = t * 3;
      WAIT4; COMPUTE_CH(kc + 0, 0); STAGE_H(kc + 3, 0);
      WAIT4; COMPUTE_CH(kc + 1, 1); STAGE_H(kc + 4, 1);
      WAIT4; COMPUTE_CH(kc + 2, 2); STAGE_H(kc + 5, 2);
    }
    WAIT4; COMPUTE_CH(12, 0); STAGE_H(15, 0);
    WAIT4; COMPUTE_CH(13, 1);
    WAIT2; COMPUTE_CH(14, 2);
    WAIT0; COMPUTE_CH(15, 0);

    // epilogue: acc[j][r] = gate j of (brow+r, hcol)
    short* hdst = hs + (size_t)sl * (BB * HH);
#pragma unroll
    for (int r = 0; r < 4; ++r) {
      const float gi = acc[0][r] + xgv[0][r];
      const float gf = acc[1][r] + xgv[1][r];
      const float gc = acc[2][r] + xgv[2][r];
      const float go = acc[3][r] + xgv[3][r];
      const float cn = sigf(gf) * cv[r] + sigf(gi) * tanhfast(gc);
      cv[r] = cn;
      hdst[(size_t)(brow + r) * HH + hcol] = f2bf(sigf(go) * tanhfast(cn));
    }
    if (sl + 1 < nsteps) {
      const int target = t0 + sl + 1;
      WAIT0;                                 // all this wave's h stores done
      __syncthreads();                       // all waves' h stores done
      if (tid == 0) {
        __builtin_amdgcn_fence(__ATOMIC_RELEASE, "agent");   // one wbL2/step
        __hip_atomic_store(&flags[ht], target, __ATOMIC_RELAXED,
                           __HIP_MEMORY_SCOPE_AGENT);
      }
      if (tid < 64) {
        while (__hip_atomic_load(&flags[tid], __ATOMIC_RELAXED,
                                 __HIP_MEMORY_SCOPE_AGENT) < target)
          __builtin_amdgcn_s_sleep(1);
      }
      __syncthreads();                       // all lanes saw all 64 flags
      if (tid == 0)
        __builtin_amdgcn_fence(__ATOMIC_ACQUIRE, "agent");   // one invL2/step
      __syncthreads();                       // inv done before h loads
    }
  }
#pragma unroll
  for (int r = 0; r < 4; ++r) cst[(size_t)(brow + r) * HH + hcol] = cv[r];
}

// ---------------- heads: wave per row ------------------------------------
__global__ __launch_bounds__(256) void heads_k(
    const short* __restrict__ hs, const short* __restrict__ Wl,
    const float* __restrict__ bl, const short* __restrict__ Wv,
    const float* __restrict__ bv, const int* __restrict__ acts,
    float* __restrict__ out, int t0) {
  const int tid = threadIdx.x, lane = tid & 63, wave = tid >> 6;
  const int r = blockIdx.x * 4 + wave;
  const int sl = r >> 8, b = r & 255;
  const int mg = b * SS + t0 + sl;
  const short* hrow = hs + (size_t)r * HH + lane * 16;
  const s16x8 hv0 = *(const s16x8*)hrow;
  const s16x8 hv1 = *(const s16x8*)(hrow + 8);
  float xv[16];
#pragma unroll
  for (int e = 0; e < 8; ++e) { xv[e] = bf2f(hv0[e]); xv[8 + e] = bf2f(hv1[e]); }

  float lg[19];
#pragma unroll
  for (int j = 0; j < 19; ++j) {
    const short* wp = (j < 18 ? Wl + (size_t)j * HH : Wv) + lane * 16;
    const s16x8 w0 = *(const s16x8*)wp;
    const s16x8 w1 = *(const s16x8*)(wp + 8);
    float s = 0.f;
#pragma unroll
    for (int e = 0; e < 8; ++e) s += xv[e] * bf2f(w0[e]) + xv[8 + e] * bf2f(w1[e]);
#pragma unroll
    for (int d = 32; d >= 1; d >>= 1) s += __shfl_xor(s, d, 64);
    lg[j] = s + (j < 18 ? bl[j] : bv[0]);
  }
  float mx = lg[0];
#pragma unroll
  for (int j = 1; j < 18; ++j) mx = fmaxf(mx, lg[j]);
  float se = 0.f;
#pragma unroll
  for (int j = 0; j < 18; ++j) se += __expf(lg[j] - mx);
  const float lse = __logf(se);
  if (lane == 0) {
    const int act = acts[mg];
    float ent = 0.f, sel = 0.f;
#pragma unroll
    for (int j = 0; j < 18; ++j) {
      const float lp = lg[j] - mx - lse;
      out[(size_t)mg * 18 + j] = lp;
      ent -= __expf(lp) * lp;
      if (j == act) sel = lp;
    }
    out[LP_OFF + mg] = sel;
    out[ENT_OFF + mg] = ent;
    out[VAL_OFF + mg] = lg[18];
  }
}

// ---------------- launch ---------------------------------------------------
extern "C" void kernel_launch(void* const* d_in, const int* in_sizes, int n_in,
                              void* d_out, int out_size, void* d_ws, size_t ws_size,
                              hipStream_t stream) {
  const float* obs    = (const float*)d_in[0];
  const float* hx     = (const float*)d_in[1];
  const float* cx     = (const float*)d_in[2];
  const int*   acts   = (const int*)d_in[3];
  const float* W_body = (const float*)d_in[4];
  const float* b_body = (const float*)d_in[5];
  const float* W_ih   = (const float*)d_in[6];
  const float* b_ih   = (const float*)d_in[7];
  const float* W_hh   = (const float*)d_in[8];
  const float* b_hh   = (const float*)d_in[9];
  const float* W_v    = (const float*)d_in[10];
  const float* b_v    = (const float*)d_in[11];
  const float* W_l    = (const float*)d_in[12];
  const float* b_l    = (const float*)d_in[13];
  float* out = (float*)d_out;
  (void)in_sizes; (void)n_in; (void)out_size;

  // Allow >64KB dynamic LDS for the scan kernel (idempotent; capture-safe).
  (void)hipFuncSetAttribute((const void*)lstm_scan,
                            hipFuncAttributeMaxDynamicSharedMemorySize, 155648);

  // Pick the largest time-chunk whose workspace footprint fits ws_size.
  const size_t FIXED = 36235264ull;      // weights + obsb + state + flags
  const size_t PER_C = 3145728ull;       // x_chunk + xg_chunk + hs_chunk
  int chunk = 32;
  while (chunk > 1 && FIXED + (size_t)chunk * PER_C > ws_size) chunk >>= 1;

  char* ws = (char*)d_ws;
  size_t off = 0;
  auto give = [&](size_t bytes) -> char* {
    char* p = ws + off;
    off += (bytes + 255) & ~(size_t)255;
    return p;
  };
  short* wb   = (short*)give((size_t)HH * OBSN * 2);
  short* wih  = (short*)give((size_t)G4 * HH * 2);
  short* whh  = (short*)give((size_t)G4 * HH * 2);
  short* wl   = (short*)give((size_t)AN * HH * 2);
  short* wv   = (short*)give((size_t)HH * 2);
  float* bsum = (float*)give((size_t)G4 * 4);
  short* obsb = (short*)give((size_t)MM * OBSN * 2);
  short* h0b  = (short*)give((size_t)BB * HH * 2);
  short* h1b  = (short*)give((size_t)BB * HH * 2);  // unused (layout keep)
  float* cbuf = (float*)give((size_t)BB * HH * 4);
  int*   barb = (int*)give(1024);
  short* xc   = (short*)give((size_t)chunk * BB * HH * 2);
  short* xgc  = (short*)give((size_t)chunk * BB * G4 * 2);
  short* hsc  = (short*)give((size_t)chunk * BB * HH * 2);
  (void)h1b;

  hipMemsetAsync(barb, 0, 1024, stream);

  prep<<<16919, 256, 0, stream>>>(obs, W_body, W_ih, W_hh, W_l, W_v, b_ih, b_hh,
                                  hx, cx, obsb, wb, wih, whh, wl, wv, bsum, h0b, cbuf);

  const int Mc = chunk * BB;
  for (int t0 = 0; t0 < SS; t0 += chunk) {
    gemm_bt<HH, OBSN, true, 1>
        <<<(Mc / 128) * (HH / 128), 256, 0, stream>>>(obsb, wb, b_body, xc, t0);
    gemm_bt<G4, HH, false, 0>
        <<<(Mc / 128) * (G4 / 128), 256, 0, stream>>>(xc, wih, bsum, xgc, 0);
    const short* hprev = (t0 == 0) ? h0b : hsc + (size_t)(chunk - 1) * BB * HH;
    lstm_scan<<<256, 256, 155648, stream>>>(whh, xgc, hsc, hprev, cbuf, barb,
                                            chunk, t0);
    heads_k<<<Mc / 4, 256, 0, stream>>>(hsc, wl, b_l, wv, b_v, acts, out, t0);
  }
}

// Round 6
// 1812.722 us; speedup vs baseline: 1.1703x; 1.1703x over previous
//
#include <hip/hip_runtime.h>

#define AS1 __attribute__((address_space(1)))
#define AS3 __attribute__((address_space(3)))

typedef __attribute__((ext_vector_type(4))) float f32x4;
typedef __attribute__((ext_vector_type(8))) short s16x8;
typedef __attribute__((ext_vector_type(4))) short s16x4;

static constexpr int BB = 256, SS = 128, OBSN = 256, HH = 1024, AN = 18;
static constexpr int MM = BB * SS;   // 32768
static constexpr int G4 = 4 * HH;    // 4096

static constexpr int LP_OFF  = MM * AN;            // 589824
static constexpr int ENT_OFF = LP_OFF + MM;        // 622592
static constexpr int VAL_OFF = ENT_OFF + MM;       // 655360

__device__ __forceinline__ short f2bf(float f) {
  unsigned u = __builtin_bit_cast(unsigned, f);
  u += 0x7FFFu + ((u >> 16) & 1u);
  return (short)(u >> 16);
}
__device__ __forceinline__ float bf2f(short s) {
  unsigned u = ((unsigned)(unsigned short)s) << 16;
  return __builtin_bit_cast(float, u);
}
__device__ __forceinline__ void gl_lds16(const void* g, void* l) {
  __builtin_amdgcn_global_load_lds((const AS1 void*)g, (AS3 void*)l, 16, 0, 0);
}
__device__ __forceinline__ float sigf(float x) {
  x = fminf(fmaxf(x, -30.f), 30.f);
  return 1.f / (1.f + __expf(-x));
}
__device__ __forceinline__ float tanhfast(float x) {
  x = fminf(fmaxf(x, -15.f), 15.f);
  float e = __expf(2.f * x);
  return (e - 1.f) / (e + 1.f);
}
__device__ __forceinline__ void cast4(const float* __restrict__ s,
                                      short* __restrict__ d, int i) {
  f32x4 v = ((const f32x4*)s)[i];
  s16x4 o;
  o[0] = f2bf(v[0]); o[1] = f2bf(v[1]); o[2] = f2bf(v[2]); o[3] = f2bf(v[3]);
  ((s16x4*)d)[i] = o;
}

// ---------------- prep: casts + bias fold + state init --------------------
__global__ __launch_bounds__(256) void prep(
    const float* __restrict__ obs, const float* __restrict__ Wb,
    const float* __restrict__ Wih, const float* __restrict__ Whh,
    const float* __restrict__ Wl, const float* __restrict__ Wv,
    const float* __restrict__ bih, const float* __restrict__ bhh,
    const float* __restrict__ hx, const float* __restrict__ cx,
    short* __restrict__ obsb, short* __restrict__ wbo, short* __restrict__ wiho,
    short* __restrict__ whho, short* __restrict__ wlo, short* __restrict__ wvo,
    float* __restrict__ bsum, short* __restrict__ h0o, float* __restrict__ co) {
  int i = blockIdx.x * 256 + threadIdx.x;   // float4 units
  if (i < 2097152) { cast4(obs, obsb, i); return; }
  i -= 2097152;
  if (i < 65536) { cast4(Wb, wbo, i); return; }
  i -= 65536;
  if (i < 1048576) { cast4(Wih, wiho, i); return; }
  i -= 1048576;
  if (i < 1048576) { cast4(Whh, whho, i); return; }
  i -= 1048576;
  if (i < 4608) { cast4(Wl, wlo, i); return; }
  i -= 4608;
  if (i < 256) { cast4(Wv, wvo, i); return; }
  i -= 256;
  if (i < 1024) {
    f32x4 a = ((const f32x4*)bih)[i];
    f32x4 b = ((const f32x4*)bhh)[i];
    ((f32x4*)bsum)[i] = a + b;
    return;
  }
  i -= 1024;
  // i < 65536: hx -> h0 bf16, cx -> c f32
  cast4(hx, h0o, i);
  ((f32x4*)co)[i] = ((const f32x4*)cx)[i];
}

// ---------------- bf16 B^T GEMM, 128x128 tile, BK=32 (m97 structure) ------
template <int N, int K, bool RELU, int REMAP>
__global__ __launch_bounds__(256, 2) void gemm_bt(
    const short* __restrict__ A, const short* __restrict__ Bw,
    const float* __restrict__ bias, short* __restrict__ C, int t0) {
  __shared__ short lA[128 * 32];
  __shared__ short lB[128 * 32];
  const int tid = threadIdx.x;
  const int lane = tid & 63, wave = tid >> 6;
  const int nTN = N / 128;
  const int tm = blockIdx.x / nTN, tn = blockIdx.x % nTN;

  const int r0 = tid >> 2;          // 0..63 staging row
  const int kc = (tid & 3) * 8;     // element offset in row

  const int m0 = tm * 128 + r0;
  const int m1 = m0 + 64;
  size_t pr0, pr1;
  if constexpr (REMAP == 1) {
    pr0 = (size_t)((m0 & (BB - 1)) * SS + t0 + (m0 >> 8));
    pr1 = (size_t)((m1 & (BB - 1)) * SS + t0 + (m1 >> 8));
  } else {
    pr0 = (size_t)m0; pr1 = (size_t)m1;
  }
  const short* a0 = A + pr0 * K + kc;
  const short* a1 = A + pr1 * K + kc;
  const short* b0 = Bw + (size_t)(tn * 128 + r0) * K + kc;
  const short* b1 = Bw + (size_t)(tn * 128 + r0 + 64) * K + kc;

  f32x4 acc[4][4];
#pragma unroll
  for (int i = 0; i < 4; ++i)
#pragma unroll
    for (int j = 0; j < 4; ++j) acc[i][j] = {0.f, 0.f, 0.f, 0.f};

  const int wr = (wave >> 1) * 64;
  const int wc = (wave & 1) * 64;
  const int fr = lane & 15;
  const int fk = (lane >> 4) * 8;

  for (int k0 = 0; k0 < K; k0 += 32) {
    __syncthreads();
    gl_lds16(a0 + k0, &lA[tid * 8]);
    gl_lds16(a1 + k0, &lA[2048 + tid * 8]);
    gl_lds16(b0 + k0, &lB[tid * 8]);
    gl_lds16(b1 + k0, &lB[2048 + tid * 8]);
    __syncthreads();
    s16x8 af[4], bfr[4];
#pragma unroll
    for (int i = 0; i < 4; ++i)
      af[i] = *(const s16x8*)&lA[(wr + i * 16 + fr) * 32 + fk];
#pragma unroll
    for (int j = 0; j < 4; ++j)
      bfr[j] = *(const s16x8*)&lB[(wc + j * 16 + fr) * 32 + fk];
#pragma unroll
    for (int i = 0; i < 4; ++i)
#pragma unroll
      for (int j = 0; j < 4; ++j)
        acc[i][j] = __builtin_amdgcn_mfma_f32_16x16x32_bf16(af[i], bfr[j], acc[i][j], 0, 0, 0);
  }

  const int orow = (lane >> 4) * 4;
#pragma unroll
  for (int i = 0; i < 4; ++i) {
#pragma unroll
    for (int j = 0; j < 4; ++j) {
      const int colg = tn * 128 + wc + j * 16 + fr;
      const float bv = bias[colg];
#pragma unroll
      for (int r = 0; r < 4; ++r) {
        const int rowg = tm * 128 + wr + i * 16 + orow + r;
        float v = acc[i][j][r] + bv;
        if (RELU) v = v > 0.f ? v : 0.f;
        C[(size_t)rowg * N + colg] = f2bf(v);
      }
    }
  }
}

// ---------------- persistent LSTM scan v4 ---------------------------------
// 256 WGs x 256 thr, 1/CU. WG = (bt: 64 batch rows, ht: 16 hcols).
// W slice (128KB) LDS-resident. h exchanged through the Infinity Cache with
// L2-BYPASS ops (sc0 sc1) -> NO fences anywhere (R4/R5's 13us/step L2
// tag-walk fences eliminated). h loaded directly into MFMA A-fragment regs
// (all 32 dwordx4/lane up-front, exact counted vmcnt per chunk).

#define HLD(o0, o1, a_, b_)                                                   \
  asm volatile("global_load_dwordx4 %0, %2, off offset:" #o0 " sc0 sc1\n\t"   \
               "global_load_dwordx4 %1, %2, off offset:" #o1 " sc0 sc1"       \
               : "=v"(a_), "=v"(b_) : "v"(hb) : "memory")

#define CHUNK(kc_, wn_, a_, b_)                                               \
  asm volatile("s_waitcnt vmcnt(" #wn_ ")" ::: "memory");                     \
  __builtin_amdgcn_sched_barrier(0);                                          \
  {                                                                           \
    _Pragma("unroll") for (int j = 0; j < 4; ++j) {                           \
      const int rowb = (j * 16 + fr) << 11;                                   \
      const s16x8 w0 = *(const s16x8*)(smem + rowb +                          \
                                       ((((kc_) * 8 + fh) ^ fr) << 4));       \
      const s16x8 w1 = *(const s16x8*)(smem + rowb +                          \
                                       ((((kc_) * 8 + 4 + fh) ^ fr) << 4));   \
      acc[j] = __builtin_amdgcn_mfma_f32_16x16x32_bf16(a_, w0, acc[j], 0, 0, 0); \
      acc[j] = __builtin_amdgcn_mfma_f32_16x16x32_bf16(b_, w1, acc[j], 0, 0, 0); \
    }                                                                         \
  }

__global__ __launch_bounds__(256, 1) void lstm_scan(
    const short* __restrict__ Whh, const short* __restrict__ xg,
    short* __restrict__ hs, const short* __restrict__ h0,
    float* __restrict__ cst, int* __restrict__ bar, int nsteps, int t0) {
  extern __shared__ char smem[];            // 128KB W only

  const int tid = threadIdx.x, lane = tid & 63, w = tid >> 6;
  const int bt = blockIdx.x >> 6, ht = blockIdx.x & 63;
  const int b0 = bt * 64, hc0 = ht * 16;
  const int fr = lane & 15, fh = lane >> 4;

  // --- W preload: LDS row r = gate(r>>4), hcol hc0+(r&15); 4-bit src swz ---
#pragma unroll 4
  for (int j = 0; j < 32; ++j) {
    const int cid = j * 256 + tid;
    const int r = cid >> 7, cc = cid & 127;
    const int wrow = (r >> 4) * HH + hc0 + (r & 15);
    gl_lds16(Whh + (size_t)wrow * HH + ((size_t)(cc ^ (r & 15)) << 3),
             smem + cid * 16);
  }
  const int brow = b0 + w * 16 + fh * 4;    // + r
  const int hcol = hc0 + fr;
  float cv[4];
#pragma unroll
  for (int r = 0; r < 4; ++r) cv[r] = cst[(size_t)(brow + r) * HH + hcol];
  int* flags = bar + bt * 64;
  asm volatile("s_waitcnt vmcnt(0)" ::: "memory");
  __syncthreads();                           // W + cv ready

  for (int sl = 0; sl < nsteps; ++sl) {
    const short* hsrc = (sl == 0) ? h0 : hs + (size_t)(sl - 1) * (BB * HH);
    const short* hb = hsrc + (size_t)(b0 + w * 16 + fr) * HH + fh * 8;

    // xg preload FIRST (16 ushort loads) so vmcnt counts below stay exact.
    float xgv[4][4];
    {
      const short* xgb = xg + (size_t)sl * BB * G4;
#pragma unroll
      for (int j = 0; j < 4; ++j)
#pragma unroll
        for (int r = 0; r < 4; ++r)
          xgv[j][r] = bf2f(xgb[(size_t)(brow + r) * G4 + j * HH + hcol]);
    }

    f32x4 acc[4];
#pragma unroll
    for (int j = 0; j < 4; ++j) acc[j] = {0.f, 0.f, 0.f, 0.f};

    s16x8 hA0, hB0, hA1, hB1, hA2, hB2, hA3, hB3, hA4, hB4, hA5, hB5, hA6, hB6,
        hA7, hB7, hA8, hB8, hA9, hB9, hA10, hB10, hA11, hB11, hA12, hB12,
        hA13, hB13, hA14, hB14, hA15, hB15;
    HLD(0, 64, hA0, hB0);       HLD(128, 192, hA1, hB1);
    HLD(256, 320, hA2, hB2);    HLD(384, 448, hA3, hB3);
    HLD(512, 576, hA4, hB4);    HLD(640, 704, hA5, hB5);
    HLD(768, 832, hA6, hB6);    HLD(896, 960, hA7, hB7);
    HLD(1024, 1088, hA8, hB8);  HLD(1152, 1216, hA9, hB9);
    HLD(1280, 1344, hA10, hB10); HLD(1408, 1472, hA11, hB11);
    HLD(1536, 1600, hA12, hB12); HLD(1664, 1728, hA13, hB13);
    HLD(1792, 1856, hA14, hB14); HLD(1920, 1984, hA15, hB15);

    CHUNK(0, 30, hA0, hB0)   CHUNK(1, 28, hA1, hB1)
    CHUNK(2, 26, hA2, hB2)   CHUNK(3, 24, hA3, hB3)
    CHUNK(4, 22, hA4, hB4)   CHUNK(5, 20, hA5, hB5)
    CHUNK(6, 18, hA6, hB6)   CHUNK(7, 16, hA7, hB7)
    CHUNK(8, 14, hA8, hB8)   CHUNK(9, 12, hA9, hB9)
    CHUNK(10, 10, hA10, hB10) CHUNK(11, 8, hA11, hB11)
    CHUNK(12, 6, hA12, hB12) CHUNK(13, 4, hA13, hB13)
    CHUNK(14, 2, hA14, hB14) CHUNK(15, 0, hA15, hB15)

    // epilogue: acc[j][r] = gate j of (brow+r, hcol); stores L2-bypassed
    short* hdst = hs + (size_t)sl * (BB * HH);
#pragma unroll
    for (int r = 0; r < 4; ++r) {
      const float gi = acc[0][r] + xgv[0][r];
      const float gf = acc[1][r] + xgv[1][r];
      const float gc = acc[2][r] + xgv[2][r];
      const float go = acc[3][r] + xgv[3][r];
      const float cn = sigf(gf) * cv[r] + sigf(gi) * tanhfast(gc);
      cv[r] = cn;
      const unsigned hv = (unsigned)(unsigned short)f2bf(sigf(go) * tanhfast(cn));
      short* hp = hdst + (size_t)(brow + r) * HH + hcol;
      asm volatile("global_store_short %0, %1, off sc0 sc1"
                   :: "v"(hp), "v"(hv) : "memory");
    }
    if (sl + 1 < nsteps) {
      const int target = t0 + sl + 1;
      asm volatile("s_waitcnt vmcnt(0)" ::: "memory");  // h at coherence point
      __syncthreads();
      if (tid == 0)
        __hip_atomic_store(&flags[ht], target, __ATOMIC_RELAXED,
                           __HIP_MEMORY_SCOPE_AGENT);
      if (tid < 64) {
        while (__hip_atomic_load(&flags[tid], __ATOMIC_RELAXED,
                                 __HIP_MEMORY_SCOPE_AGENT) < target)
          __builtin_amdgcn_s_sleep(1);
      }
      __syncthreads();
    }
  }
#pragma unroll
  for (int r = 0; r < 4; ++r) cst[(size_t)(brow + r) * HH + hcol] = cv[r];
}

// ---------------- heads: wave per row ------------------------------------
__global__ __launch_bounds__(256) void heads_k(
    const short* __restrict__ hs, const short* __restrict__ Wl,
    const float* __restrict__ bl, const short* __restrict__ Wv,
    const float* __restrict__ bv, const int* __restrict__ acts,
    float* __restrict__ out, int t0) {
  const int tid = threadIdx.x, lane = tid & 63, wave = tid >> 6;
  const int r = blockIdx.x * 4 + wave;
  const int sl = r >> 8, b = r & 255;
  const int mg = b * SS + t0 + sl;
  const short* hrow = hs + (size_t)r * HH + lane * 16;
  const s16x8 hv0 = *(const s16x8*)hrow;
  const s16x8 hv1 = *(const s16x8*)(hrow + 8);
  float xv[16];
#pragma unroll
  for (int e = 0; e < 8; ++e) { xv[e] = bf2f(hv0[e]); xv[8 + e] = bf2f(hv1[e]); }

  float lg[19];
#pragma unroll
  for (int j = 0; j < 19; ++j) {
    const short* wp = (j < 18 ? Wl + (size_t)j * HH : Wv) + lane * 16;
    const s16x8 w0 = *(const s16x8*)wp;
    const s16x8 w1 = *(const s16x8*)(wp + 8);
    float s = 0.f;
#pragma unroll
    for (int e = 0; e < 8; ++e) s += xv[e] * bf2f(w0[e]) + xv[8 + e] * bf2f(w1[e]);
#pragma unroll
    for (int d = 32; d >= 1; d >>= 1) s += __shfl_xor(s, d, 64);
    lg[j] = s + (j < 18 ? bl[j] : bv[0]);
  }
  float mx = lg[0];
#pragma unroll
  for (int j = 1; j < 18; ++j) mx = fmaxf(mx, lg[j]);
  float se = 0.f;
#pragma unroll
  for (int j = 0; j < 18; ++j) se += __expf(lg[j] - mx);
  const float lse = __logf(se);
  if (lane == 0) {
    const int act = acts[mg];
    float ent = 0.f, sel = 0.f;
#pragma unroll
    for (int j = 0; j < 18; ++j) {
      const float lp = lg[j] - mx - lse;
      out[(size_t)mg * 18 + j] = lp;
      ent -= __expf(lp) * lp;
      if (j == act) sel = lp;
    }
    out[LP_OFF + mg] = sel;
    out[ENT_OFF + mg] = ent;
    out[VAL_OFF + mg] = lg[18];
  }
}

// ---------------- launch ---------------------------------------------------
extern "C" void kernel_launch(void* const* d_in, const int* in_sizes, int n_in,
                              void* d_out, int out_size, void* d_ws, size_t ws_size,
                              hipStream_t stream) {
  const float* obs    = (const float*)d_in[0];
  const float* hx     = (const float*)d_in[1];
  const float* cx     = (const float*)d_in[2];
  const int*   acts   = (const int*)d_in[3];
  const float* W_body = (const float*)d_in[4];
  const float* b_body = (const float*)d_in[5];
  const float* W_ih   = (const float*)d_in[6];
  const float* b_ih   = (const float*)d_in[7];
  const float* W_hh   = (const float*)d_in[8];
  const float* b_hh   = (const float*)d_in[9];
  const float* W_v    = (const float*)d_in[10];
  const float* b_v    = (const float*)d_in[11];
  const float* W_l    = (const float*)d_in[12];
  const float* b_l    = (const float*)d_in[13];
  float* out = (float*)d_out;
  (void)in_sizes; (void)n_in; (void)out_size;

  // Allow >64KB dynamic LDS for the scan kernel (idempotent; capture-safe).
  (void)hipFuncSetAttribute((const void*)lstm_scan,
                            hipFuncAttributeMaxDynamicSharedMemorySize, 131072);

  // Pick the largest time-chunk whose workspace footprint fits ws_size.
  const size_t FIXED = 36235264ull;      // weights + obsb + state + flags
  const size_t PER_C = 3145728ull;       // x_chunk + xg_chunk + hs_chunk
  int chunk = 32;
  while (chunk > 1 && FIXED + (size_t)chunk * PER_C > ws_size) chunk >>= 1;

  char* ws = (char*)d_ws;
  size_t off = 0;
  auto give = [&](size_t bytes) -> char* {
    char* p = ws + off;
    off += (bytes + 255) & ~(size_t)255;
    return p;
  };
  short* wb   = (short*)give((size_t)HH * OBSN * 2);
  short* wih  = (short*)give((size_t)G4 * HH * 2);
  short* whh  = (short*)give((size_t)G4 * HH * 2);
  short* wl   = (short*)give((size_t)AN * HH * 2);
  short* wv   = (short*)give((size_t)HH * 2);
  float* bsum = (float*)give((size_t)G4 * 4);
  short* obsb = (short*)give((size_t)MM * OBSN * 2);
  short* h0b  = (short*)give((size_t)BB * HH * 2);
  short* h1b  = (short*)give((size_t)BB * HH * 2);  // unused (layout keep)
  float* cbuf = (float*)give((size_t)BB * HH * 4);
  int*   barb = (int*)give(1024);
  short* xc   = (short*)give((size_t)chunk * BB * HH * 2);
  short* xgc  = (short*)give((size_t)chunk * BB * G4 * 2);
  short* hsc  = (short*)give((size_t)chunk * BB * HH * 2);
  (void)h1b;

  hipMemsetAsync(barb, 0, 1024, stream);

  prep<<<16919, 256, 0, stream>>>(obs, W_body, W_ih, W_hh, W_l, W_v, b_ih, b_hh,
                                  hx, cx, obsb, wb, wih, whh, wl, wv, bsum, h0b, cbuf);

  const int Mc = chunk * BB;
  for (int t0 = 0; t0 < SS; t0 += chunk) {
    gemm_bt<HH, OBSN, true, 1>
        <<<(Mc / 128) * (HH / 128), 256, 0, stream>>>(obsb, wb, b_body, xc, t0);
    gemm_bt<G4, HH, false, 0>
        <<<(Mc / 128) * (G4 / 128), 256, 0, stream>>>(xc, wih, bsum, xgc, 0);
    const short* hprev = (t0 == 0) ? h0b : hsc + (size_t)(chunk - 1) * BB * HH;
    lstm_scan<<<256, 256, 131072, stream>>>(whh, xgc, hsc, hprev, cbuf, barb,
                                            chunk, t0);
    heads_k<<<Mc / 4, 256, 0, stream>>>(hsc, wl, b_l, wv, b_v, acts, out, t0);
  }
}

// Round 7
// 1578.341 us; speedup vs baseline: 1.3441x; 1.1485x over previous
//
#include <hip/hip_runtime.h>

#define AS1 __attribute__((address_space(1)))
#define AS3 __attribute__((address_space(3)))

typedef __attribute__((ext_vector_type(4))) float f32x4;
typedef __attribute__((ext_vector_type(8))) short s16x8;
typedef __attribute__((ext_vector_type(4))) short s16x4;

static constexpr int BB = 256, SS = 128, OBSN = 256, HH = 1024, AN = 18;
static constexpr int MM = BB * SS;   // 32768
static constexpr int G4 = 4 * HH;    // 4096

static constexpr int LP_OFF  = MM * AN;            // 589824
static constexpr int ENT_OFF = LP_OFF + MM;        // 622592
static constexpr int VAL_OFF = ENT_OFF + MM;       // 655360

__device__ __forceinline__ short f2bf(float f) {
  unsigned u = __builtin_bit_cast(unsigned, f);
  u += 0x7FFFu + ((u >> 16) & 1u);
  return (short)(u >> 16);
}
__device__ __forceinline__ float bf2f(short s) {
  unsigned u = ((unsigned)(unsigned short)s) << 16;
  return __builtin_bit_cast(float, u);
}
__device__ __forceinline__ void gl_lds16(const void* g, void* l) {
  __builtin_amdgcn_global_load_lds((const AS1 void*)g, (AS3 void*)l, 16, 0, 0);
}
__device__ __forceinline__ float sigf(float x) {
  x = fminf(fmaxf(x, -30.f), 30.f);
  return 1.f / (1.f + __expf(-x));
}
__device__ __forceinline__ float tanhfast(float x) {
  x = fminf(fmaxf(x, -15.f), 15.f);
  float e = __expf(2.f * x);
  return (e - 1.f) / (e + 1.f);
}
__device__ __forceinline__ void cast4(const float* __restrict__ s,
                                      short* __restrict__ d, int i) {
  f32x4 v = ((const f32x4*)s)[i];
  s16x4 o;
  o[0] = f2bf(v[0]); o[1] = f2bf(v[1]); o[2] = f2bf(v[2]); o[3] = f2bf(v[3]);
  ((s16x4*)d)[i] = o;
}

// ---------------- prep: casts + bias fold + state init --------------------
__global__ __launch_bounds__(256) void prep(
    const float* __restrict__ obs, const float* __restrict__ Wb,
    const float* __restrict__ Wih, const float* __restrict__ Whh,
    const float* __restrict__ Wl, const float* __restrict__ Wv,
    const float* __restrict__ bih, const float* __restrict__ bhh,
    const float* __restrict__ hx, const float* __restrict__ cx,
    short* __restrict__ obsb, short* __restrict__ wbo, short* __restrict__ wiho,
    short* __restrict__ whho, short* __restrict__ wlo, short* __restrict__ wvo,
    float* __restrict__ bsum, short* __restrict__ h0o, float* __restrict__ co) {
  int i = blockIdx.x * 256 + threadIdx.x;   // float4 units
  if (i < 2097152) { cast4(obs, obsb, i); return; }
  i -= 2097152;
  if (i < 65536) { cast4(Wb, wbo, i); return; }
  i -= 65536;
  if (i < 1048576) { cast4(Wih, wiho, i); return; }
  i -= 1048576;
  if (i < 1048576) { cast4(Whh, whho, i); return; }
  i -= 1048576;
  if (i < 4608) { cast4(Wl, wlo, i); return; }
  i -= 4608;
  if (i < 256) { cast4(Wv, wvo, i); return; }
  i -= 256;
  if (i < 1024) {
    f32x4 a = ((const f32x4*)bih)[i];
    f32x4 b = ((const f32x4*)bhh)[i];
    ((f32x4*)bsum)[i] = a + b;
    return;
  }
  i -= 1024;
  // i < 65536: hx -> h0 bf16, cx -> c f32
  cast4(hx, h0o, i);
  ((f32x4*)co)[i] = ((const f32x4*)cx)[i];
}

// ---------------- bf16 B^T GEMM, 128x128 tile, BK=32 (m97 structure) ------
template <int N, int K, bool RELU, int REMAP>
__global__ __launch_bounds__(256, 2) void gemm_bt(
    const short* __restrict__ A, const short* __restrict__ Bw,
    const float* __restrict__ bias, short* __restrict__ C, int t0) {
  __shared__ short lA[128 * 32];
  __shared__ short lB[128 * 32];
  const int tid = threadIdx.x;
  const int lane = tid & 63, wave = tid >> 6;
  const int nTN = N / 128;
  const int tm = blockIdx.x / nTN, tn = blockIdx.x % nTN;

  const int r0 = tid >> 2;          // 0..63 staging row
  const int kc = (tid & 3) * 8;     // element offset in row

  const int m0 = tm * 128 + r0;
  const int m1 = m0 + 64;
  size_t pr0, pr1;
  if constexpr (REMAP == 1) {
    pr0 = (size_t)((m0 & (BB - 1)) * SS + t0 + (m0 >> 8));
    pr1 = (size_t)((m1 & (BB - 1)) * SS + t0 + (m1 >> 8));
  } else {
    pr0 = (size_t)m0; pr1 = (size_t)m1;
  }
  const short* a0 = A + pr0 * K + kc;
  const short* a1 = A + pr1 * K + kc;
  const short* b0 = Bw + (size_t)(tn * 128 + r0) * K + kc;
  const short* b1 = Bw + (size_t)(tn * 128 + r0 + 64) * K + kc;

  f32x4 acc[4][4];
#pragma unroll
  for (int i = 0; i < 4; ++i)
#pragma unroll
    for (int j = 0; j < 4; ++j) acc[i][j] = {0.f, 0.f, 0.f, 0.f};

  const int wr = (wave >> 1) * 64;
  const int wc = (wave & 1) * 64;
  const int fr = lane & 15;
  const int fk = (lane >> 4) * 8;

  for (int k0 = 0; k0 < K; k0 += 32) {
    __syncthreads();
    gl_lds16(a0 + k0, &lA[tid * 8]);
    gl_lds16(a1 + k0, &lA[2048 + tid * 8]);
    gl_lds16(b0 + k0, &lB[tid * 8]);
    gl_lds16(b1 + k0, &lB[2048 + tid * 8]);
    __syncthreads();
    s16x8 af[4], bfr[4];
#pragma unroll
    for (int i = 0; i < 4; ++i)
      af[i] = *(const s16x8*)&lA[(wr + i * 16 + fr) * 32 + fk];
#pragma unroll
    for (int j = 0; j < 4; ++j)
      bfr[j] = *(const s16x8*)&lB[(wc + j * 16 + fr) * 32 + fk];
#pragma unroll
    for (int i = 0; i < 4; ++i)
#pragma unroll
      for (int j = 0; j < 4; ++j)
        acc[i][j] = __builtin_amdgcn_mfma_f32_16x16x32_bf16(af[i], bfr[j], acc[i][j], 0, 0, 0);
  }

  const int orow = (lane >> 4) * 4;
#pragma unroll
  for (int i = 0; i < 4; ++i) {
#pragma unroll
    for (int j = 0; j < 4; ++j) {
      const int colg = tn * 128 + wc + j * 16 + fr;
      const float bv = bias[colg];
#pragma unroll
      for (int r = 0; r < 4; ++r) {
        const int rowg = tm * 128 + wr + i * 16 + orow + r;
        float v = acc[i][j][r] + bv;
        if (RELU) v = v > 0.f ? v : 0.f;
        C[(size_t)rowg * N + colg] = f2bf(v);
      }
    }
  }
}

// ---------------- persistent LSTM scan v5 ---------------------------------
// 256 WGs x 256 thr, 1/CU. WG = (bt: 64 batch rows, ht: 16 hcols).
// W slice (128KB) LDS-resident. h stores write-through to LLC (sc0 sc1);
// h LOADS are plain cached (L2 amplification absorbed locally; safe because
// each hs[sl] is write-once-then-read within a launch and launch boundaries
// invalidate L1/L2). xg(s+1) prefetched under the barrier wait with a counted
// vmcnt(16) pinning store completion before the flag.

#define HLD(o0, o1, a_, b_)                                                   \
  asm volatile("global_load_dwordx4 %0, %2, off offset:" #o0 "\n\t"           \
               "global_load_dwordx4 %1, %2, off offset:" #o1                  \
               : "=v"(a_), "=v"(b_) : "v"(hb) : "memory")

#define CHUNK(kc_, wn_, a_, b_)                                               \
  asm volatile("s_waitcnt vmcnt(" #wn_ ")" ::: "memory");                     \
  __builtin_amdgcn_sched_barrier(0);                                          \
  {                                                                           \
    _Pragma("unroll") for (int j = 0; j < 4; ++j) {                           \
      const int rowb = (j * 16 + fr) << 11;                                   \
      const s16x8 w0 = *(const s16x8*)(smem + rowb +                          \
                                       ((((kc_) * 8 + fh) ^ fr) << 4));       \
      const s16x8 w1 = *(const s16x8*)(smem + rowb +                          \
                                       ((((kc_) * 8 + 4 + fh) ^ fr) << 4));   \
      acc[j] = __builtin_amdgcn_mfma_f32_16x16x32_bf16(a_, w0, acc[j], 0, 0, 0); \
      acc[j] = __builtin_amdgcn_mfma_f32_16x16x32_bf16(b_, w1, acc[j], 0, 0, 0); \
    }                                                                         \
  }

__global__ __launch_bounds__(256, 1) void lstm_scan(
    const short* __restrict__ Whh, const short* __restrict__ xg,
    short* __restrict__ hs, const short* __restrict__ h0,
    float* __restrict__ cst, int* __restrict__ bar, int nsteps, int t0) {
  extern __shared__ char smem[];            // 128KB W only

  const int tid = threadIdx.x, lane = tid & 63, w = tid >> 6;
  const int bt = blockIdx.x >> 6, ht = blockIdx.x & 63;
  const int b0 = bt * 64, hc0 = ht * 16;
  const int fr = lane & 15, fh = lane >> 4;
  const int brow = b0 + w * 16 + fh * 4;    // + r
  const int hcol = hc0 + fr;

  // xg preload for step 0 (overlaps W preload below)
  float xgv[4][4];
#pragma unroll
  for (int j = 0; j < 4; ++j)
#pragma unroll
    for (int r = 0; r < 4; ++r)
      xgv[j][r] = bf2f(xg[(size_t)(brow + r) * G4 + j * HH + hcol]);

  // --- W preload: LDS row r = gate(r>>4), hcol hc0+(r&15); 4-bit src swz ---
#pragma unroll 4
  for (int j = 0; j < 32; ++j) {
    const int cid = j * 256 + tid;
    const int r = cid >> 7, cc = cid & 127;
    const int wrow = (r >> 4) * HH + hc0 + (r & 15);
    gl_lds16(Whh + (size_t)wrow * HH + ((size_t)(cc ^ (r & 15)) << 3),
             smem + cid * 16);
  }
  float cv[4];
#pragma unroll
  for (int r = 0; r < 4; ++r) cv[r] = cst[(size_t)(brow + r) * HH + hcol];
  int* flags = bar + bt * 64;
  asm volatile("s_waitcnt vmcnt(0)" ::: "memory");
  __syncthreads();                           // W + cv + xgv(0) ready

  for (int sl = 0; sl < nsteps; ++sl) {
    const short* hsrc = (sl == 0) ? h0 : hs + (size_t)(sl - 1) * (BB * HH);
    const short* hb = hsrc + (size_t)(b0 + w * 16 + fr) * HH + fh * 8;

    f32x4 acc[4];
#pragma unroll
    for (int j = 0; j < 4; ++j) acc[j] = {0.f, 0.f, 0.f, 0.f};

    s16x8 hA0, hB0, hA1, hB1, hA2, hB2, hA3, hB3, hA4, hB4, hA5, hB5, hA6, hB6,
        hA7, hB7, hA8, hB8, hA9, hB9, hA10, hB10, hA11, hB11, hA12, hB12,
        hA13, hB13, hA14, hB14, hA15, hB15;
    HLD(0, 64, hA0, hB0);       HLD(128, 192, hA1, hB1);
    HLD(256, 320, hA2, hB2);    HLD(384, 448, hA3, hB3);
    HLD(512, 576, hA4, hB4);    HLD(640, 704, hA5, hB5);
    HLD(768, 832, hA6, hB6);    HLD(896, 960, hA7, hB7);
    HLD(1024, 1088, hA8, hB8);  HLD(1152, 1216, hA9, hB9);
    HLD(1280, 1344, hA10, hB10); HLD(1408, 1472, hA11, hB11);
    HLD(1536, 1600, hA12, hB12); HLD(1664, 1728, hA13, hB13);
    HLD(1792, 1856, hA14, hB14); HLD(1920, 1984, hA15, hB15);

    // waves that carry 16 prefetch loads into this step retire them first:
    // vmcnt(30-2k) always implies h loads 1..2k+2 complete for both cases.
    CHUNK(0, 30, hA0, hB0)   CHUNK(1, 28, hA1, hB1)
    CHUNK(2, 26, hA2, hB2)   CHUNK(3, 24, hA3, hB3)
    CHUNK(4, 22, hA4, hB4)   CHUNK(5, 20, hA5, hB5)
    CHUNK(6, 18, hA6, hB6)   CHUNK(7, 16, hA7, hB7)
    CHUNK(8, 14, hA8, hB8)   CHUNK(9, 12, hA9, hB9)
    CHUNK(10, 10, hA10, hB10) CHUNK(11, 8, hA11, hB11)
    CHUNK(12, 6, hA12, hB12) CHUNK(13, 4, hA13, hB13)
    CHUNK(14, 2, hA14, hB14) CHUNK(15, 0, hA15, hB15)

    // epilogue: acc[j][r] = gate j of (brow+r, hcol); stores write-through
    short* hdst = hs + (size_t)sl * (BB * HH);
#pragma unroll
    for (int r = 0; r < 4; ++r) {
      const float gi = acc[0][r] + xgv[0][r];
      const float gf = acc[1][r] + xgv[1][r];
      const float gc = acc[2][r] + xgv[2][r];
      const float go = acc[3][r] + xgv[3][r];
      const float cn = sigf(gf) * cv[r] + sigf(gi) * tanhfast(gc);
      cv[r] = cn;
      const unsigned hv = (unsigned)(unsigned short)f2bf(sigf(go) * tanhfast(cn));
      short* hp = hdst + (size_t)(brow + r) * HH + hcol;
      asm volatile("global_store_short %0, %1, off sc0 sc1"
                   :: "v"(hp), "v"(hv) : "memory");
    }
    if (sl + 1 < nsteps) {
      // xg(s+1) prefetch: 16 loads pinned between store-asms and vmcnt(16);
      // their latency hides under the flag/poll wait.
      const short* xgb = xg + (size_t)(sl + 1) * BB * G4;
      float xgn[4][4];
#pragma unroll
      for (int j = 0; j < 4; ++j)
#pragma unroll
        for (int r = 0; r < 4; ++r)
          xgn[j][r] = bf2f(xgb[(size_t)(brow + r) * G4 + j * HH + hcol]);
      asm volatile("s_waitcnt vmcnt(16)" ::: "memory");  // 4 oldest = stores
      __syncthreads();
      const int target = t0 + sl + 1;
      if (tid == 0)
        __hip_atomic_store(&flags[ht], target, __ATOMIC_RELAXED,
                           __HIP_MEMORY_SCOPE_AGENT);
      if (tid < 64) {
        while (__hip_atomic_load(&flags[tid], __ATOMIC_RELAXED,
                                 __HIP_MEMORY_SCOPE_AGENT) < target)
          __builtin_amdgcn_s_sleep(1);
      }
      __syncthreads();
#pragma unroll
      for (int j = 0; j < 4; ++j)
#pragma unroll
        for (int r = 0; r < 4; ++r) xgv[j][r] = xgn[j][r];
    }
  }
#pragma unroll
  for (int r = 0; r < 4; ++r) cst[(size_t)(brow + r) * HH + hcol] = cv[r];
}

// ---------------- heads: wave per row ------------------------------------
__global__ __launch_bounds__(256) void heads_k(
    const short* __restrict__ hs, const short* __restrict__ Wl,
    const float* __restrict__ bl, const short* __restrict__ Wv,
    const float* __restrict__ bv, const int* __restrict__ acts,
    float* __restrict__ out, int t0) {
  const int tid = threadIdx.x, lane = tid & 63, wave = tid >> 6;
  const int r = blockIdx.x * 4 + wave;
  const int sl = r >> 8, b = r & 255;
  const int mg = b * SS + t0 + sl;
  const short* hrow = hs + (size_t)r * HH + lane * 16;
  const s16x8 hv0 = *(const s16x8*)hrow;
  const s16x8 hv1 = *(const s16x8*)(hrow + 8);
  float xv[16];
#pragma unroll
  for (int e = 0; e < 8; ++e) { xv[e] = bf2f(hv0[e]); xv[8 + e] = bf2f(hv1[e]); }

  float lg[19];
#pragma unroll
  for (int j = 0; j < 19; ++j) {
    const short* wp = (j < 18 ? Wl + (size_t)j * HH : Wv) + lane * 16;
    const s16x8 w0 = *(const s16x8*)wp;
    const s16x8 w1 = *(const s16x8*)(wp + 8);
    float s = 0.f;
#pragma unroll
    for (int e = 0; e < 8; ++e) s += xv[e] * bf2f(w0[e]) + xv[8 + e] * bf2f(w1[e]);
#pragma unroll
    for (int d = 32; d >= 1; d >>= 1) s += __shfl_xor(s, d, 64);
    lg[j] = s + (j < 18 ? bl[j] : bv[0]);
  }
  float mx = lg[0];
#pragma unroll
  for (int j = 1; j < 18; ++j) mx = fmaxf(mx, lg[j]);
  float se = 0.f;
#pragma unroll
  for (int j = 0; j < 18; ++j) se += __expf(lg[j] - mx);
  const float lse = __logf(se);
  if (lane == 0) {
    const int act = acts[mg];
    float ent = 0.f, sel = 0.f;
#pragma unroll
    for (int j = 0; j < 18; ++j) {
      const float lp = lg[j] - mx - lse;
      out[(size_t)mg * 18 + j] = lp;
      ent -= __expf(lp) * lp;
      if (j == act) sel = lp;
    }
    out[LP_OFF + mg] = sel;
    out[ENT_OFF + mg] = ent;
    out[VAL_OFF + mg] = lg[18];
  }
}

// ---------------- launch ---------------------------------------------------
extern "C" void kernel_launch(void* const* d_in, const int* in_sizes, int n_in,
                              void* d_out, int out_size, void* d_ws, size_t ws_size,
                              hipStream_t stream) {
  const float* obs    = (const float*)d_in[0];
  const float* hx     = (const float*)d_in[1];
  const float* cx     = (const float*)d_in[2];
  const int*   acts   = (const int*)d_in[3];
  const float* W_body = (const float*)d_in[4];
  const float* b_body = (const float*)d_in[5];
  const float* W_ih   = (const float*)d_in[6];
  const float* b_ih   = (const float*)d_in[7];
  const float* W_hh   = (const float*)d_in[8];
  const float* b_hh   = (const float*)d_in[9];
  const float* W_v    = (const float*)d_in[10];
  const float* b_v    = (const float*)d_in[11];
  const float* W_l    = (const float*)d_in[12];
  const float* b_l    = (const float*)d_in[13];
  float* out = (float*)d_out;
  (void)in_sizes; (void)n_in; (void)out_size;

  // Allow >64KB dynamic LDS for the scan kernel (idempotent; capture-safe).
  (void)hipFuncSetAttribute((const void*)lstm_scan,
                            hipFuncAttributeMaxDynamicSharedMemorySize, 131072);

  // Pick the largest time-chunk whose workspace footprint fits ws_size.
  const size_t FIXED = 36235264ull;      // weights + obsb + state + flags
  const size_t PER_C = 3145728ull;       // x_chunk + xg_chunk + hs_chunk
  int chunk = 64;
  while (chunk > 1 && FIXED + (size_t)chunk * PER_C > ws_size) chunk >>= 1;

  char* ws = (char*)d_ws;
  size_t off = 0;
  auto give = [&](size_t bytes) -> char* {
    char* p = ws + off;
    off += (bytes + 255) & ~(size_t)255;
    return p;
  };
  short* wb   = (short*)give((size_t)HH * OBSN * 2);
  short* wih  = (short*)give((size_t)G4 * HH * 2);
  short* whh  = (short*)give((size_t)G4 * HH * 2);
  short* wl   = (short*)give((size_t)AN * HH * 2);
  short* wv   = (short*)give((size_t)HH * 2);
  float* bsum = (float*)give((size_t)G4 * 4);
  short* obsb = (short*)give((size_t)MM * OBSN * 2);
  short* h0b  = (short*)give((size_t)BB * HH * 2);
  short* h1b  = (short*)give((size_t)BB * HH * 2);  // unused (layout keep)
  float* cbuf = (float*)give((size_t)BB * HH * 4);
  int*   barb = (int*)give(1024);
  short* xc   = (short*)give((size_t)chunk * BB * HH * 2);
  short* xgc  = (short*)give((size_t)chunk * BB * G4 * 2);
  short* hsc  = (short*)give((size_t)chunk * BB * HH * 2);
  (void)h1b;

  hipMemsetAsync(barb, 0, 1024, stream);

  prep<<<16919, 256, 0, stream>>>(obs, W_body, W_ih, W_hh, W_l, W_v, b_ih, b_hh,
                                  hx, cx, obsb, wb, wih, whh, wl, wv, bsum, h0b, cbuf);

  const int Mc = chunk * BB;
  for (int t0 = 0; t0 < SS; t0 += chunk) {
    gemm_bt<HH, OBSN, true, 1>
        <<<(Mc / 128) * (HH / 128), 256, 0, stream>>>(obsb, wb, b_body, xc, t0);
    gemm_bt<G4, HH, false, 0>
        <<<(Mc / 128) * (G4 / 128), 256, 0, stream>>>(xc, wih, bsum, xgc, 0);
    const short* hprev = (t0 == 0) ? h0b : hsc + (size_t)(chunk - 1) * BB * HH;
    lstm_scan<<<256, 256, 131072, stream>>>(whh, xgc, hsc, hprev, cbuf, barb,
                                            chunk, t0);
    heads_k<<<Mc / 4, 256, 0, stream>>>(hsc, wl, b_l, wv, b_v, acts, out, t0);
  }
}

// Round 8
// 1477.098 us; speedup vs baseline: 1.4362x; 1.0685x over previous
//
#include <hip/hip_runtime.h>

#define AS1 __attribute__((address_space(1)))
#define AS3 __attribute__((address_space(3)))

typedef __attribute__((ext_vector_type(4))) float f32x4;
typedef __attribute__((ext_vector_type(8))) short s16x8;
typedef __attribute__((ext_vector_type(4))) short s16x4;

static constexpr int BB = 256, SS = 128, OBSN = 256, HH = 1024, AN = 18;
static constexpr int MM = BB * SS;   // 32768
static constexpr int G4 = 4 * HH;    // 4096

static constexpr int LP_OFF  = MM * AN;            // 589824
static constexpr int ENT_OFF = LP_OFF + MM;        // 622592
static constexpr int VAL_OFF = ENT_OFF + MM;       // 655360

__device__ __forceinline__ short f2bf(float f) {
  unsigned u = __builtin_bit_cast(unsigned, f);
  u += 0x7FFFu + ((u >> 16) & 1u);
  return (short)(u >> 16);
}
__device__ __forceinline__ float bf2f(short s) {
  unsigned u = ((unsigned)(unsigned short)s) << 16;
  return __builtin_bit_cast(float, u);
}
__device__ __forceinline__ void gl_lds16(const void* g, void* l) {
  __builtin_amdgcn_global_load_lds((const AS1 void*)g, (AS3 void*)l, 16, 0, 0);
}
__device__ __forceinline__ float sigf(float x) {
  x = fminf(fmaxf(x, -30.f), 30.f);
  return 1.f / (1.f + __expf(-x));
}
__device__ __forceinline__ float tanhfast(float x) {
  x = fminf(fmaxf(x, -15.f), 15.f);
  float e = __expf(2.f * x);
  return (e - 1.f) / (e + 1.f);
}
__device__ __forceinline__ void cast4(const float* __restrict__ s,
                                      short* __restrict__ d, int i) {
  f32x4 v = ((const f32x4*)s)[i];
  s16x4 o;
  o[0] = f2bf(v[0]); o[1] = f2bf(v[1]); o[2] = f2bf(v[2]); o[3] = f2bf(v[3]);
  ((s16x4*)d)[i] = o;
}

// ---------------- prep: casts + bias fold + state init --------------------
__global__ __launch_bounds__(256) void prep(
    const float* __restrict__ obs, const float* __restrict__ Wb,
    const float* __restrict__ Wih, const float* __restrict__ Whh,
    const float* __restrict__ Wl, const float* __restrict__ Wv,
    const float* __restrict__ bih, const float* __restrict__ bhh,
    const float* __restrict__ hx, const float* __restrict__ cx,
    short* __restrict__ obsb, short* __restrict__ wbo, short* __restrict__ wiho,
    short* __restrict__ whho, short* __restrict__ wlo, short* __restrict__ wvo,
    float* __restrict__ bsum, short* __restrict__ h0o, float* __restrict__ co) {
  int i = blockIdx.x * 256 + threadIdx.x;   // float4 units
  if (i < 2097152) { cast4(obs, obsb, i); return; }
  i -= 2097152;
  if (i < 65536) { cast4(Wb, wbo, i); return; }
  i -= 65536;
  if (i < 1048576) { cast4(Wih, wiho, i); return; }
  i -= 1048576;
  if (i < 1048576) { cast4(Whh, whho, i); return; }
  i -= 1048576;
  if (i < 4608) { cast4(Wl, wlo, i); return; }
  i -= 4608;
  if (i < 256) { cast4(Wv, wvo, i); return; }
  i -= 256;
  if (i < 1024) {
    f32x4 a = ((const f32x4*)bih)[i];
    f32x4 b = ((const f32x4*)bhh)[i];
    ((f32x4*)bsum)[i] = a + b;
    return;
  }
  i -= 1024;
  // i < 65536: hx -> h0 bf16, cx -> c f32
  cast4(hx, h0o, i);
  ((f32x4*)co)[i] = ((const f32x4*)cx)[i];
}

// ---------------- bf16 B^T GEMM, 128x128 tile, BK=32 (m97 structure) ------
template <int N, int K, bool RELU, int REMAP>
__global__ __launch_bounds__(256, 2) void gemm_bt(
    const short* __restrict__ A, const short* __restrict__ Bw,
    const float* __restrict__ bias, short* __restrict__ C, int t0) {
  __shared__ short lA[128 * 32];
  __shared__ short lB[128 * 32];
  const int tid = threadIdx.x;
  const int lane = tid & 63, wave = tid >> 6;
  const int nTN = N / 128;
  const int tm = blockIdx.x / nTN, tn = blockIdx.x % nTN;

  const int r0 = tid >> 2;          // 0..63 staging row
  const int kc = (tid & 3) * 8;     // element offset in row

  const int m0 = tm * 128 + r0;
  const int m1 = m0 + 64;
  size_t pr0, pr1;
  if constexpr (REMAP == 1) {
    pr0 = (size_t)((m0 & (BB - 1)) * SS + t0 + (m0 >> 8));
    pr1 = (size_t)((m1 & (BB - 1)) * SS + t0 + (m1 >> 8));
  } else {
    pr0 = (size_t)m0; pr1 = (size_t)m1;
  }
  const short* a0 = A + pr0 * K + kc;
  const short* a1 = A + pr1 * K + kc;
  const short* b0 = Bw + (size_t)(tn * 128 + r0) * K + kc;
  const short* b1 = Bw + (size_t)(tn * 128 + r0 + 64) * K + kc;

  f32x4 acc[4][4];
#pragma unroll
  for (int i = 0; i < 4; ++i)
#pragma unroll
    for (int j = 0; j < 4; ++j) acc[i][j] = {0.f, 0.f, 0.f, 0.f};

  const int wr = (wave >> 1) * 64;
  const int wc = (wave & 1) * 64;
  const int fr = lane & 15;
  const int fk = (lane >> 4) * 8;

  for (int k0 = 0; k0 < K; k0 += 32) {
    __syncthreads();
    gl_lds16(a0 + k0, &lA[tid * 8]);
    gl_lds16(a1 + k0, &lA[2048 + tid * 8]);
    gl_lds16(b0 + k0, &lB[tid * 8]);
    gl_lds16(b1 + k0, &lB[2048 + tid * 8]);
    __syncthreads();
    s16x8 af[4], bfr[4];
#pragma unroll
    for (int i = 0; i < 4; ++i)
      af[i] = *(const s16x8*)&lA[(wr + i * 16 + fr) * 32 + fk];
#pragma unroll
    for (int j = 0; j < 4; ++j)
      bfr[j] = *(const s16x8*)&lB[(wc + j * 16 + fr) * 32 + fk];
#pragma unroll
    for (int i = 0; i < 4; ++i)
#pragma unroll
      for (int j = 0; j < 4; ++j)
        acc[i][j] = __builtin_amdgcn_mfma_f32_16x16x32_bf16(af[i], bfr[j], acc[i][j], 0, 0, 0);
  }

  const int orow = (lane >> 4) * 4;
#pragma unroll
  for (int i = 0; i < 4; ++i) {
#pragma unroll
    for (int j = 0; j < 4; ++j) {
      const int colg = tn * 128 + wc + j * 16 + fr;
      const float bv = bias[colg];
#pragma unroll
      for (int r = 0; r < 4; ++r) {
        const int rowg = tm * 128 + wr + i * 16 + orow + r;
        float v = acc[i][j][r] + bv;
        if (RELU) v = v > 0.f ? v : 0.f;
        C[(size_t)rowg * N + colg] = f2bf(v);
      }
    }
  }
}

// ---------------- persistent LSTM scan v6 ---------------------------------
// 256 WGs x 256 thr, 1/CU. WG = (bt: 64 batch rows, ht: 16 hcols).
// W slice (128KB) LDS-resident. h stores write-through (sc0 sc1); h loads
// cached. Flags per producer; relaxed poll.
// NEW vs v5: (a) xg prefetch DRAINED inside the barrier window (vmcnt(0)
// after poll) so post-barrier vmcnt(30-2k) counts pure h-loads -> xg HBM
// latency off the critical path; (b) template PIN A/B: PIN=1 confines each
// bt-group to one XCD pair (blockIdx%8 round-robin assumption; bijective
// either way, perf-only).

#define HLD(o0, o1, a_, b_)                                                   \
  asm volatile("global_load_dwordx4 %0, %2, off offset:" #o0 "\n\t"           \
               "global_load_dwordx4 %1, %2, off offset:" #o1                  \
               : "=v"(a_), "=v"(b_) : "v"(hb) : "memory")

#define CHUNK(kc_, wn_, a_, b_)                                               \
  asm volatile("s_waitcnt vmcnt(" #wn_ ")" ::: "memory");                     \
  __builtin_amdgcn_sched_barrier(0);                                          \
  {                                                                           \
    _Pragma("unroll") for (int j = 0; j < 4; ++j) {                           \
      const int rowb = (j * 16 + fr) << 11;                                   \
      const s16x8 w0 = *(const s16x8*)(smem + rowb +                          \
                                       ((((kc_) * 8 + fh) ^ fr) << 4));       \
      const s16x8 w1 = *(const s16x8*)(smem + rowb +                          \
                                       ((((kc_) * 8 + 4 + fh) ^ fr) << 4));   \
      acc[j] = __builtin_amdgcn_mfma_f32_16x16x32_bf16(a_, w0, acc[j], 0, 0, 0); \
      acc[j] = __builtin_amdgcn_mfma_f32_16x16x32_bf16(b_, w1, acc[j], 0, 0, 0); \
    }                                                                         \
  }

template <int PIN>
__global__ __launch_bounds__(256, 1) void lstm_scan(
    const short* __restrict__ Whh, const short* __restrict__ xg,
    short* __restrict__ hs, const short* __restrict__ h0,
    float* __restrict__ cst, int* __restrict__ bar, int nsteps, int t0) {
  extern __shared__ char smem[];            // 128KB W only

  const int tid = threadIdx.x, lane = tid & 63, w = tid >> 6;
  const int g = blockIdx.x;
  int bt, ht;
  if constexpr (PIN == 1) {
    bt = (g & 7) >> 1;                      // bt-group on XCD pair {2bt,2bt+1}
    ht = ((g & 1) << 5) | (g >> 3);
  } else {
    bt = g >> 6;
    ht = g & 63;
  }
  const int b0 = bt * 64, hc0 = ht * 16;
  const int fr = lane & 15, fh = lane >> 4;
  const int brow = b0 + w * 16 + fh * 4;    // + r
  const int hcol = hc0 + fr;

  // xg preload for step 0 (overlaps W preload below)
  float xgv[4][4];
#pragma unroll
  for (int j = 0; j < 4; ++j)
#pragma unroll
    for (int r = 0; r < 4; ++r)
      xgv[j][r] = bf2f(xg[(size_t)(brow + r) * G4 + j * HH + hcol]);

  // --- W preload: LDS row r = gate(r>>4), hcol hc0+(r&15); 4-bit src swz ---
#pragma unroll 4
  for (int j = 0; j < 32; ++j) {
    const int cid = j * 256 + tid;
    const int r = cid >> 7, cc = cid & 127;
    const int wrow = (r >> 4) * HH + hc0 + (r & 15);
    gl_lds16(Whh + (size_t)wrow * HH + ((size_t)(cc ^ (r & 15)) << 3),
             smem + cid * 16);
  }
  float cv[4];
#pragma unroll
  for (int r = 0; r < 4; ++r) cv[r] = cst[(size_t)(brow + r) * HH + hcol];
  int* flags = bar + bt * 64;
  asm volatile("s_waitcnt vmcnt(0)" ::: "memory");
  __syncthreads();                           // W + cv + xgv(0) ready

  for (int sl = 0; sl < nsteps; ++sl) {
    const short* hsrc = (sl == 0) ? h0 : hs + (size_t)(sl - 1) * (BB * HH);
    const short* hb = hsrc + (size_t)(b0 + w * 16 + fr) * HH + fh * 8;

    f32x4 acc[4];
#pragma unroll
    for (int j = 0; j < 4; ++j) acc[j] = {0.f, 0.f, 0.f, 0.f};

    s16x8 hA0, hB0, hA1, hB1, hA2, hB2, hA3, hB3, hA4, hB4, hA5, hB5, hA6, hB6,
        hA7, hB7, hA8, hB8, hA9, hB9, hA10, hB10, hA11, hB11, hA12, hB12,
        hA13, hB13, hA14, hB14, hA15, hB15;
    HLD(0, 64, hA0, hB0);       HLD(128, 192, hA1, hB1);
    HLD(256, 320, hA2, hB2);    HLD(384, 448, hA3, hB3);
    HLD(512, 576, hA4, hB4);    HLD(640, 704, hA5, hB5);
    HLD(768, 832, hA6, hB6);    HLD(896, 960, hA7, hB7);
    HLD(1024, 1088, hA8, hB8);  HLD(1152, 1216, hA9, hB9);
    HLD(1280, 1344, hA10, hB10); HLD(1408, 1472, hA11, hB11);
    HLD(1536, 1600, hA12, hB12); HLD(1664, 1728, hA13, hB13);
    HLD(1792, 1856, hA14, hB14); HLD(1920, 1984, hA15, hB15);

    // VMEM queue is pure h-loads here (xg drained inside barrier window):
    // vmcnt(30-2k) => h chunks 0..k resident.
    CHUNK(0, 30, hA0, hB0)   CHUNK(1, 28, hA1, hB1)
    CHUNK(2, 26, hA2, hB2)   CHUNK(3, 24, hA3, hB3)
    CHUNK(4, 22, hA4, hB4)   CHUNK(5, 20, hA5, hB5)
    CHUNK(6, 18, hA6, hB6)   CHUNK(7, 16, hA7, hB7)
    CHUNK(8, 14, hA8, hB8)   CHUNK(9, 12, hA9, hB9)
    CHUNK(10, 10, hA10, hB10) CHUNK(11, 8, hA11, hB11)
    CHUNK(12, 6, hA12, hB12) CHUNK(13, 4, hA13, hB13)
    CHUNK(14, 2, hA14, hB14) CHUNK(15, 0, hA15, hB15)

    // epilogue: acc[j][r] = gate j of (brow+r, hcol); stores write-through
    short* hdst = hs + (size_t)sl * (BB * HH);
#pragma unroll
    for (int r = 0; r < 4; ++r) {
      const float gi = acc[0][r] + xgv[0][r];
      const float gf = acc[1][r] + xgv[1][r];
      const float gc = acc[2][r] + xgv[2][r];
      const float go = acc[3][r] + xgv[3][r];
      const float cn = sigf(gf) * cv[r] + sigf(gi) * tanhfast(gc);
      cv[r] = cn;
      const unsigned hv = (unsigned)(unsigned short)f2bf(sigf(go) * tanhfast(cn));
      short* hp = hdst + (size_t)(brow + r) * HH + hcol;
      asm volatile("global_store_short %0, %1, off sc0 sc1"
                   :: "v"(hp), "v"(hv) : "memory");
    }
    if (sl + 1 < nsteps) {
      // xg(s+1) prefetch; issued before the store-wait so its HBM latency
      // overlaps the flag/poll window; fully drained before leaving barrier.
      const short* xgb = xg + (size_t)(sl + 1) * BB * G4;
      float xgn[4][4];
#pragma unroll
      for (int j = 0; j < 4; ++j)
#pragma unroll
        for (int r = 0; r < 4; ++r)
          xgn[j][r] = bf2f(xgb[(size_t)(brow + r) * G4 + j * HH + hcol]);
      asm volatile("s_waitcnt vmcnt(16)" ::: "memory");  // 4 oldest = stores
      __syncthreads();
      const int target = t0 + sl + 1;
      if (tid == 0)
        __hip_atomic_store(&flags[ht], target, __ATOMIC_RELAXED,
                           __HIP_MEMORY_SCOPE_AGENT);
      if (tid < 64) {
        while (__hip_atomic_load(&flags[tid], __ATOMIC_RELAXED,
                                 __HIP_MEMORY_SCOPE_AGENT) < target)
          __builtin_amdgcn_s_sleep(1);
      }
      asm volatile("s_waitcnt vmcnt(0)" ::: "memory");   // drain own xg here
      __syncthreads();
#pragma unroll
      for (int j = 0; j < 4; ++j)
#pragma unroll
        for (int r = 0; r < 4; ++r) xgv[j][r] = xgn[j][r];
    }
  }
#pragma unroll
  for (int r = 0; r < 4; ++r) cst[(size_t)(brow + r) * HH + hcol] = cv[r];
}

// ---------------- heads: wave per row ------------------------------------
__global__ __launch_bounds__(256) void heads_k(
    const short* __restrict__ hs, const short* __restrict__ Wl,
    const float* __restrict__ bl, const short* __restrict__ Wv,
    const float* __restrict__ bv, const int* __restrict__ acts,
    float* __restrict__ out, int t0) {
  const int tid = threadIdx.x, lane = tid & 63, wave = tid >> 6;
  const int r = blockIdx.x * 4 + wave;
  const int sl = r >> 8, b = r & 255;
  const int mg = b * SS + t0 + sl;
  const short* hrow = hs + (size_t)r * HH + lane * 16;
  const s16x8 hv0 = *(const s16x8*)hrow;
  const s16x8 hv1 = *(const s16x8*)(hrow + 8);
  float xv[16];
#pragma unroll
  for (int e = 0; e < 8; ++e) { xv[e] = bf2f(hv0[e]); xv[8 + e] = bf2f(hv1[e]); }

  float lg[19];
#pragma unroll
  for (int j = 0; j < 19; ++j) {
    const short* wp = (j < 18 ? Wl + (size_t)j * HH : Wv) + lane * 16;
    const s16x8 w0 = *(const s16x8*)wp;
    const s16x8 w1 = *(const s16x8*)(wp + 8);
    float s = 0.f;
#pragma unroll
    for (int e = 0; e < 8; ++e) s += xv[e] * bf2f(w0[e]) + xv[8 + e] * bf2f(w1[e]);
#pragma unroll
    for (int d = 32; d >= 1; d >>= 1) s += __shfl_xor(s, d, 64);
    lg[j] = s + (j < 18 ? bl[j] : bv[0]);
  }
  float mx = lg[0];
#pragma unroll
  for (int j = 1; j < 18; ++j) mx = fmaxf(mx, lg[j]);
  float se = 0.f;
#pragma unroll
  for (int j = 0; j < 18; ++j) se += __expf(lg[j] - mx);
  const float lse = __logf(se);
  if (lane == 0) {
    const int act = acts[mg];
    float ent = 0.f, sel = 0.f;
#pragma unroll
    for (int j = 0; j < 18; ++j) {
      const float lp = lg[j] - mx - lse;
      out[(size_t)mg * 18 + j] = lp;
      ent -= __expf(lp) * lp;
      if (j == act) sel = lp;
    }
    out[LP_OFF + mg] = sel;
    out[ENT_OFF + mg] = ent;
    out[VAL_OFF + mg] = lg[18];
  }
}

// ---------------- launch ---------------------------------------------------
extern "C" void kernel_launch(void* const* d_in, const int* in_sizes, int n_in,
                              void* d_out, int out_size, void* d_ws, size_t ws_size,
                              hipStream_t stream) {
  const float* obs    = (const float*)d_in[0];
  const float* hx     = (const float*)d_in[1];
  const float* cx     = (const float*)d_in[2];
  const int*   acts   = (const int*)d_in[3];
  const float* W_body = (const float*)d_in[4];
  const float* b_body = (const float*)d_in[5];
  const float* W_ih   = (const float*)d_in[6];
  const float* b_ih   = (const float*)d_in[7];
  const float* W_hh   = (const float*)d_in[8];
  const float* b_hh   = (const float*)d_in[9];
  const float* W_v    = (const float*)d_in[10];
  const float* b_v    = (const float*)d_in[11];
  const float* W_l    = (const float*)d_in[12];
  const float* b_l    = (const float*)d_in[13];
  float* out = (float*)d_out;
  (void)in_sizes; (void)n_in; (void)out_size;

  // Allow >64KB dynamic LDS for the scan kernels (idempotent; capture-safe).
  (void)hipFuncSetAttribute((const void*)lstm_scan<1>,
                            hipFuncAttributeMaxDynamicSharedMemorySize, 131072);
  (void)hipFuncSetAttribute((const void*)lstm_scan<0>,
                            hipFuncAttributeMaxDynamicSharedMemorySize, 131072);

  // Pick the largest time-chunk whose workspace footprint fits ws_size.
  const size_t FIXED = 36235264ull;      // weights + obsb + state + flags
  const size_t PER_C = 3145728ull;       // x_chunk + xg_chunk + hs_chunk
  int chunk = 64;
  while (chunk > 1 && FIXED + (size_t)chunk * PER_C > ws_size) chunk >>= 1;

  char* ws = (char*)d_ws;
  size_t off = 0;
  auto give = [&](size_t bytes) -> char* {
    char* p = ws + off;
    off += (bytes + 255) & ~(size_t)255;
    return p;
  };
  short* wb   = (short*)give((size_t)HH * OBSN * 2);
  short* wih  = (short*)give((size_t)G4 * HH * 2);
  short* whh  = (short*)give((size_t)G4 * HH * 2);
  short* wl   = (short*)give((size_t)AN * HH * 2);
  short* wv   = (short*)give((size_t)HH * 2);
  float* bsum = (float*)give((size_t)G4 * 4);
  short* obsb = (short*)give((size_t)MM * OBSN * 2);
  short* h0b  = (short*)give((size_t)BB * HH * 2);
  short* h1b  = (short*)give((size_t)BB * HH * 2);  // unused (layout keep)
  float* cbuf = (float*)give((size_t)BB * HH * 4);
  int*   barb = (int*)give(1024);
  short* xc   = (short*)give((size_t)chunk * BB * HH * 2);
  short* xgc  = (short*)give((size_t)chunk * BB * G4 * 2);
  short* hsc  = (short*)give((size_t)chunk * BB * HH * 2);
  (void)h1b;

  hipMemsetAsync(barb, 0, 1024, stream);

  prep<<<16919, 256, 0, stream>>>(obs, W_body, W_ih, W_hh, W_l, W_v, b_ih, b_hh,
                                  hx, cx, obsb, wb, wih, whh, wl, wv, bsum, h0b, cbuf);

  const int Mc = chunk * BB;
  int launchIdx = 0;
  for (int t0 = 0; t0 < SS; t0 += chunk, ++launchIdx) {
    gemm_bt<HH, OBSN, true, 1>
        <<<(Mc / 128) * (HH / 128), 256, 0, stream>>>(obsb, wb, b_body, xc, t0);
    gemm_bt<G4, HH, false, 0>
        <<<(Mc / 128) * (G4 / 128), 256, 0, stream>>>(xc, wih, bsum, xgc, 0);
    const short* hprev = (t0 == 0) ? h0b : hsc + (size_t)(chunk - 1) * BB * HH;
    if ((launchIdx & 1) == 0)
      lstm_scan<1><<<256, 256, 131072, stream>>>(whh, xgc, hsc, hprev, cbuf,
                                                 barb, chunk, t0);
    else
      lstm_scan<0><<<256, 256, 131072, stream>>>(whh, xgc, hsc, hprev, cbuf,
                                                 barb, chunk, t0);
    heads_k<<<Mc / 4, 256, 0, stream>>>(hsc, wl, b_l, wv, b_v, acts, out, t0);
  }
}